// Round 4
// baseline (363.563 us; speedup 1.0000x reference)
//
#include <hip/hip_runtime.h>

// CRF forward: B=512, T=1024, N=64. fwd/bwd split, one wave per chain.
// Round 14: DPP partial-output matvec + E PRE-PERMUTED IN LDS, loaded as
// 16 NAMED f4 registers.
// Round 12/13 post-mortem: E2[4][8] two-level array with elementwise
// XOR-indexed init never got SROA-promoted -> E lived in memory; the loop
// re-read 64 E values/step (~1000 cyc/step); VGPR_Count=56 both rounds and
// the asm pin on array elements pinned copies, not storage. The ONLY
// pattern proven register-resident (rounds 10/11, VGPR=88) is contiguous
// f4 pointer loads into individually NAMED f4 variables. So: one-time
// staging writes each thread's 64 E values in DPP-gather order to
// Eperm[tid][68]; lane loads eb[0..15] into named EA0..EA15, pins them.
// Inner loop: 15 xor-DPP row-gather + 32 v_pk_fma + permlane32 pair-sum +
// ds_swizzle xor16 reduce + 3 selects. Zero E traffic per step.
// Math (verified absmax 0.0 in rounds 10/12/13): exp-domain recurrence
//   a'_j = (sum_i a_i E_ij) * w_j, exponent-only rescale every 4 steps,
//   out = ln2 * (off_f + off_b + log2(sum_i a_i b_i)).

typedef float f2 __attribute__((ext_vector_type(2)));
typedef float f4 __attribute__((ext_vector_type(4)));

constexpr int Tt = 1024;
constexpr int Nn = 64;
constexpr int ES  = 68;  // Erow stride (floats)
constexpr int EPS = 68;  // Eperm per-thread stride (floats), 272B = 17*16B
constexpr float LN2 = 0.69314718055994530942f;

template<int CTRL>
__device__ __forceinline__ float dppf(float x) {
    return __uint_as_float((unsigned)__builtin_amdgcn_update_dpp(
        0, (int)__float_as_uint(x), CTRL, 0xF, 0xF, false));
}

// lane L gets value of lane L^16 (within each 32-lane group).
__device__ __forceinline__ float swz16(float x) {
    return __uint_as_float((unsigned)__builtin_amdgcn_ds_swizzle(
        (int)__float_as_uint(x), 0x401F));
}

// Pair-sum across the 32-lane halves, order-robust (swap with copy, add
// both outputs). s_nop 1 guards the VALU-write -> cross-lane-read hazard.
__device__ __forceinline__ float xsum32(float x) {
    float a = x, b = x;
    asm("s_nop 1\n\tv_permlane32_swap_b32 %0, %1" : "+v"(a), "+v"(b));
    return a + b;
}

// m -> XOR mask s_m realizable by the DPP ladder {1,2,7,8}.
__device__ __forceinline__ int smask(int m) {
    return (((m & 1) ? 1 : 0) ^ ((m & 2) ? 2 : 0)
          ^ ((m & 4) ? 7 : 0) ^ ((m & 8) ? 8 : 0));
}

__global__ __launch_bounds__(128, 1) void crf_fwd(
    const float* __restrict__ unary,
    const int*   __restrict__ lengths,
    const float* __restrict__ trans,
    float*       __restrict__ out)
{
    const int b    = blockIdx.x;
    const int tid  = threadIdx.x;
    const int w    = tid >> 6;   // 0 = forward wave, 1 = backward wave
    const int lane = tid & 63;
    const int p    = lane & 15;
    const int r    = lane >> 4;

    __shared__ float Erow[Nn * ES];     // Erow[i*ES+j] = exp(trans[i][j])
    __shared__ float Eperm[128 * EPS];  // per-thread E in DPP-gather order
    __shared__ float shb[Nn];           // beta at midpoint (combine)
    __shared__ int   sh_off_b;          // bwd exponent offset

    // Phase 1: stage E = exp(trans) row-major (coalesced global reads).
    #pragma unroll
    for (int c = 0; c < (Nn * Nn) / 128; ++c) {
        int idx = c * 128 + tid;
        Erow[(idx >> 6) * ES + (idx & 63)] = __expf(trans[idx]);
    }
    __syncthreads();

    // Phase 2: write this thread's 64 E values in gather order:
    //   v = g*16 + m,  i = 16r + (p^s_m),  o = p + 16g
    //   fwd uses M[o][i] = E[i][o] (a' = E^T a); bwd M[o][i] = E[o][i].
    float* ep = &Eperm[tid * EPS];
    #pragma unroll
    for (int v = 0; v < 64; ++v) {
        int g = v >> 4, m = v & 15;
        int i = 16 * r + (p ^ smask(m));
        int o = p + 16 * g;
        ep[v] = (w == 0) ? Erow[i * ES + o] : Erow[o * ES + i];
    }
    // Same-thread DS write->read is in-order; no barrier needed.

    // Phase 3: contiguous f4 loads into NAMED registers (the pattern proven
    // register-resident in rounds 10/11), then pin.
    const f4* eb = (const f4*)ep;
    f4 EA0  = eb[0],  EA1  = eb[1],  EA2  = eb[2],  EA3  = eb[3];
    f4 EA4  = eb[4],  EA5  = eb[5],  EA6  = eb[6],  EA7  = eb[7];
    f4 EA8  = eb[8],  EA9  = eb[9],  EA10 = eb[10], EA11 = eb[11];
    f4 EA12 = eb[12], EA13 = eb[13], EA14 = eb[14], EA15 = eb[15];
    asm volatile("" : "+v"(EA0),  "+v"(EA1),  "+v"(EA2),  "+v"(EA3),
                      "+v"(EA4),  "+v"(EA5),  "+v"(EA6),  "+v"(EA7),
                      "+v"(EA8),  "+v"(EA9),  "+v"(EA10), "+v"(EA11),
                      "+v"(EA12), "+v"(EA13), "+v"(EA14), "+v"(EA15));

    int L = lengths[b];
    L = L < 1 ? 1 : (L > Tt ? Tt : L);
    const int m2 = (L - 1) >> 1;

    const float* ub = unary + (size_t)b * Tt * Nn;

    const int trips = (w == 0) ? m2 : (L - 1 - m2);
    const int tbase = (w == 0) ? 1 : (L - 1);
    const int dir   = (w == 0) ? 1 : -1;

    // Exp-domain state + exponent offset.
    float acc = (w == 0) ? __expf(ub[lane]) : 1.0f;
    int   off = 0;

    // 8-step lookahead: wq = exp'd w for steps s0..s0+3,
    //                   uq = raw u for steps s0+4..s0+7.
    const int smax = trips > 0 ? trips - 1 : 0;
    float wq0, wq1, wq2, wq3, uq0, uq1, uq2, uq3;
    {
        int c0 = 0 < smax ? 0 : smax, c1 = 1 < smax ? 1 : smax;
        int c2 = 2 < smax ? 2 : smax, c3 = 3 < smax ? 3 : smax;
        wq0 = __expf(ub[(tbase + dir * c0) * Nn + lane]);
        wq1 = __expf(ub[(tbase + dir * c1) * Nn + lane]);
        wq2 = __expf(ub[(tbase + dir * c2) * Nn + lane]);
        wq3 = __expf(ub[(tbase + dir * c3) * Nn + lane]);
        int c4 = 4 < smax ? 4 : smax, c5 = 5 < smax ? 5 : smax;
        int c6 = 6 < smax ? 6 : smax, c7 = 7 < smax ? 7 : smax;
        uq0 = ub[(tbase + dir * c4) * Nn + lane];
        uq1 = ub[(tbase + dir * c5) * Nn + lane];
        uq2 = ub[(tbase + dir * c6) * Nn + lane];
        uq3 = ub[(tbase + dir * c7) * Nn + lane];
    }

    for (int s0 = 0; s0 < trips; s0 += 4) {
        // Issue raw loads 8 ahead; exp the 4-ahead batch. Both off-chain.
        float un0, un1, un2, un3, wn0, wn1, wn2, wn3;
        {
            int c0 = s0 + 8,  c1 = s0 + 9,  c2 = s0 + 10, c3 = s0 + 11;
            c0 = c0 > smax ? smax : c0;  c1 = c1 > smax ? smax : c1;
            c2 = c2 > smax ? smax : c2;  c3 = c3 > smax ? smax : c3;
            un0 = ub[(tbase + dir * c0) * Nn + lane];
            un1 = ub[(tbase + dir * c1) * Nn + lane];
            un2 = ub[(tbase + dir * c2) * Nn + lane];
            un3 = ub[(tbase + dir * c3) * Nn + lane];
        }
        wn0 = __expf(uq0); wn1 = __expf(uq1);
        wn2 = __expf(uq2); wn3 = __expf(uq3);

        #pragma unroll
        for (int k = 0; k < 4; ++k) {
            if (s0 + k >= trips) break;  // wave-uniform

            float wk = (k == 0) ? wq0 : (k == 1) ? wq1 : (k == 2) ? wq2 : wq3;

            // fwd: a' = (E^T a) * w   (w on output)
            // bwd: a' = E (w * a)     (w on input)
            float src = (w != 0) ? acc * wk : acc;

            // DPP row-gather (xor ladder). gpq holds (s_{2q}, s_{2q+1}).
            f2 gp0, gp1, gp2, gp3, gp4, gp5, gp6, gp7;
            gp0[0] = src;                    // s=0
            gp0[1] = dppf<0xB1>(gp0[0]);     // s=1  quad_perm [1,0,3,2]
            gp1[0] = dppf<0x4E>(gp0[0]);     // s=2  quad_perm [2,3,0,1]
            gp1[1] = dppf<0x4E>(gp0[1]);     // s=3
            gp2[0] = dppf<0x141>(gp0[0]);    // s=7  row_half_mirror
            gp2[1] = dppf<0x141>(gp0[1]);    // s=6
            gp3[0] = dppf<0x141>(gp1[0]);    // s=5
            gp3[1] = dppf<0x141>(gp1[1]);    // s=4
            gp4[0] = dppf<0x128>(gp0[0]);    // s=8  row_ror:8 (== xor8)
            gp4[1] = dppf<0x128>(gp0[1]);    // s=9
            gp5[0] = dppf<0x128>(gp1[0]);    // s=10
            gp5[1] = dppf<0x128>(gp1[1]);    // s=11
            gp6[0] = dppf<0x128>(gp2[0]);    // s=15
            gp6[1] = dppf<0x128>(gp2[1]);    // s=14
            gp7[0] = dppf<0x128>(gp3[0]);    // s=13
            gp7[1] = dppf<0x128>(gp3[1]);    // s=12

            // Partials per output group g: even-q chain (aA), odd-q (aB).
            // E f2s: q=2h -> EA{4g+h}.xy, q=2h+1 -> EA{4g+h}.zw.
            f2 aA0 = gp0 * EA0.xy;  aA0 = gp2 * EA1.xy + aA0;
            aA0 = gp4 * EA2.xy + aA0;  aA0 = gp6 * EA3.xy + aA0;
            f2 aB0 = gp1 * EA0.zw;  aB0 = gp3 * EA1.zw + aB0;
            aB0 = gp5 * EA2.zw + aB0;  aB0 = gp7 * EA3.zw + aB0;

            f2 aA1 = gp0 * EA4.xy;  aA1 = gp2 * EA5.xy + aA1;
            aA1 = gp4 * EA6.xy + aA1;  aA1 = gp6 * EA7.xy + aA1;
            f2 aB1 = gp1 * EA4.zw;  aB1 = gp3 * EA5.zw + aB1;
            aB1 = gp5 * EA6.zw + aB1;  aB1 = gp7 * EA7.zw + aB1;

            f2 aA2 = gp0 * EA8.xy;  aA2 = gp2 * EA9.xy + aA2;
            aA2 = gp4 * EA10.xy + aA2;  aA2 = gp6 * EA11.xy + aA2;
            f2 aB2 = gp1 * EA8.zw;  aB2 = gp3 * EA9.zw + aB2;
            aB2 = gp5 * EA10.zw + aB2;  aB2 = gp7 * EA11.zw + aB2;

            f2 aA3 = gp0 * EA12.xy;  aA3 = gp2 * EA13.xy + aA3;
            aA3 = gp4 * EA14.xy + aA3;  aA3 = gp6 * EA15.xy + aA3;
            f2 aB3 = gp1 * EA12.zw;  aB3 = gp3 * EA13.zw + aB3;
            aB3 = gp5 * EA14.zw + aB3;  aB3 = gp7 * EA15.zw + aB3;

            // Cross-row reduce: stride-32 (permlane pair-sum) then
            // stride-16 (swizzle xor16), replicated over 4-lane groups.
            f2 t0 = aA0 + aB0, t1 = aA1 + aB1;
            f2 t2 = aA2 + aB2, t3 = aA3 + aB3;
            float s1_0 = xsum32(t0[0] + t0[1]);
            float s1_1 = xsum32(t1[0] + t1[1]);
            float s1_2 = xsum32(t2[0] + t2[1]);
            float s1_3 = xsum32(t3[0] + t3[1]);
            float z0 = s1_0 + swz16(s1_0);
            float z1 = s1_1 + swz16(s1_1);
            float z2 = s1_2 + swz16(s1_2);
            float z3 = s1_3 + swz16(s1_3);
            // Keep the group with g == own row r (r bits: lane&16, lane&32).
            float zl = (lane & 16) ? z1 : z0;
            float zh = (lane & 16) ? z3 : z2;
            float z  = (lane & 32) ? zh : zl;

            acc = (w == 0) ? z * wk : z;
        }

        // Exact exponent-only rescale (once per 4 steps; keeps fp32 in
        // range: worst drift 4 steps * ~14 bits + ~10 bits lane spread).
        {
            unsigned s0b = (unsigned)__builtin_amdgcn_readfirstlane(
                (int)__float_as_uint(acc));
            int e = (int)((s0b >> 23) & 0xFF) - 127;
            off += e;
            acc *= __uint_as_float((unsigned)(127 - e) << 23);
        }

        wq0 = wn0; wq1 = wn1; wq2 = wn2; wq3 = wn3;
        uq0 = un0; uq1 = un1; uq2 = un2; uq3 = un3;
    }

    // Combine: out[b] = ln2 * (off_f + off_b + log2(sum_i a_i * b_i)).
    if (w == 1) {
        shb[lane] = acc;
        if (lane == 0) sh_off_b = off;
    }
    __syncthreads();
    if (w == 0) {
        float v = acc * shb[lane];
        float ssum = v;
        #pragma unroll
        for (int k = 32; k >= 1; k >>= 1)
            ssum += __shfl_xor(ssum, k, 64);
        if (lane == 0) {
            float l2 = __builtin_amdgcn_logf(ssum);  // v_log_f32 = log2
            out[b] = LN2 * ((float)(off + sh_off_b) + l2);
        }
    }
}

extern "C" void kernel_launch(void* const* d_in, const int* in_sizes, int n_in,
                              void* d_out, int out_size, void* d_ws, size_t ws_size,
                              hipStream_t stream) {
    const float* unary   = (const float*)d_in[0];
    const int*   lengths = (const int*)d_in[1];
    const float* trans   = (const float*)d_in[2];
    float*       out     = (float*)d_out;

    const int Bb = in_sizes[1];  // 512
    crf_fwd<<<Bb, 128, 0, stream>>>(unary, lengths, trans, out);
}